// Round 11
// baseline (3941.420 us; speedup 1.0000x reference)
//
#include <hip/hip_runtime.h>
#include <hip/hip_fp16.h>

#define F 128
#define BETA  0.9f
#define LEAKY 0.2f

#define BSH 6          // rows per bucket = 64
#define RBK 64
#define NBMAX 2048     // max buckets (n<=131072)
#define BT  4096       // edges per bin tile
#define CMASK 0x1FFFF

// ---- zero an int array ----
__global__ __launch_bounds__(256) void zero_ints(int* __restrict__ p, int n) {
    int i = blockIdx.x * 256 + threadIdx.x;
    int st = gridDim.x * 256;
    for (; i < n; i += st) p[i] = 0;
}

// ---- fused: f1/f2 projections + fp32->fp16 convert of x; one wave per row ----
__global__ __launch_bounds__(256) void featconv(const float* __restrict__ x,
                                                const float* __restrict__ a,
                                                float* __restrict__ f1,
                                                float* __restrict__ f2,
                                                __half2* __restrict__ xh, int n) {
    int w = (blockIdx.x * blockDim.x + threadIdx.x) >> 6;
    int lane = threadIdx.x & 63;
    if (w >= n) return;
    const float2* xr = (const float2*)(x + (size_t)w * F);
    float2 v  = xr[lane];
    float2 A1 = ((const float2*)a)[lane];
    float2 A2 = ((const float2*)a)[64 + lane];
    float d1 = v.x * A1.x + v.y * A1.y;
    float d2 = v.x * A2.x + v.y * A2.y;
    for (int o = 32; o; o >>= 1) {
        d1 += __shfl_xor(d1, o);
        d2 += __shfl_xor(d2, o);
    }
    xh[(size_t)w * 64 + lane] = __float22half2_rn(v);
    if (lane == 0) { f1[w] = d1; f2[w] = d2; }
}

// ---- per-bucket edge histogram (LDS-staged, 2048 buckets) ----
__global__ __launch_bounds__(256) void bucket_hist(const int* __restrict__ erow,
                                                   int* __restrict__ bcnt, int e, int nb) {
    __shared__ int h[NBMAX];
    for (int b = threadIdx.x; b < NBMAX; b += 256) h[b] = 0;
    __syncthreads();
    int i = blockIdx.x * 256 + threadIdx.x;
    int st = gridDim.x * 256;
    for (; i < e; i += st) atomicAdd(&h[erow[i] >> BSH], 1);
    __syncthreads();
    for (int b = threadIdx.x; b < nb; b += 256)
        if (h[b]) atomicAdd(&bcnt[b], h[b]);
}

// ---- scan bucket counts -> base & cursor (single block, 1024 threads, pair scan) ----
__global__ __launch_bounds__(1024) void bucket_scan(const int* __restrict__ bcnt,
                                                    int* __restrict__ base,
                                                    int* __restrict__ cursor,
                                                    int nb) {
    __shared__ int arr[1024];
    int t = threadIdx.x;
    int v0 = (2 * t     < nb) ? bcnt[2 * t]     : 0;
    int v1 = (2 * t + 1 < nb) ? bcnt[2 * t + 1] : 0;
    int ps = v0 + v1;
    arr[t] = ps; __syncthreads();
    for (int off = 1; off < 1024; off <<= 1) {
        int add = (t >= off) ? arr[t - off] : 0;
        __syncthreads();
        arr[t] += add;
        __syncthreads();
    }
    int ex = arr[t] - ps;
    if (2 * t     <= nb) { base[2 * t]     = ex;      cursor[2 * t]     = ex; }
    if (2 * t + 1 <= nb) { base[2 * t + 1] = ex + v0; cursor[2 * t + 1] = ex + v0; }
}

// ---- bin: bucket-group edges (coalesced writes); compute w = exp(leaky(f1+f2)) here ----
// binned[dst] = ((row&63)<<17 | col, w_bits); binw[dst] = 0.5*adj*w
__global__ __launch_bounds__(256) void bin_edges(const int* __restrict__ erow,
                                                 const int* __restrict__ ecol,
                                                 const float* __restrict__ adj,
                                                 const float* __restrict__ f1,
                                                 const float* __restrict__ f2,
                                                 int* __restrict__ cursor,
                                                 int2* __restrict__ binned,
                                                 float* __restrict__ binw, int e) {
    __shared__ int tcnt[NBMAX], toff[NBMAX], res[NBMAX], tcur[NBMAX];
    __shared__ int arr[256];
    __shared__ short sidx[BT];
    int tid = threadIdx.x;
    int i0 = blockIdx.x * BT;
    int m = e - i0; if (m > BT) m = BT;
    for (int b = tid; b < NBMAX; b += 256) tcnt[b] = 0;
    __syncthreads();
    for (int k = tid; k < m; k += 256) atomicAdd(&tcnt[erow[i0 + k] >> BSH], 1);
    __syncthreads();
    // scan tcnt[2048] -> toff (exclusive): 8 consecutive per thread + HS over 256
    int loc[8]; int s8 = 0; int b8 = tid * 8;
    #pragma unroll
    for (int k = 0; k < 8; k++) { loc[k] = tcnt[b8 + k]; s8 += loc[k]; }
    arr[tid] = s8; __syncthreads();
    for (int off = 1; off < 256; off <<= 1) {
        int add = (tid >= off) ? arr[tid - off] : 0;
        __syncthreads();
        arr[tid] += add;
        __syncthreads();
    }
    int ex = arr[tid] - s8;
    #pragma unroll
    for (int k = 0; k < 8; k++) { toff[b8 + k] = ex; ex += loc[k]; }
    __syncthreads();
    for (int b = tid; b < NBMAX; b += 256) {
        if (tcnt[b] > 0) res[b] = atomicAdd(&cursor[b], tcnt[b]);
        tcur[b] = 0;
    }
    __syncthreads();
    for (int k = tid; k < m; k += 256) {
        int b = erow[i0 + k] >> BSH;
        int rk = atomicAdd(&tcur[b], 1);
        sidx[toff[b] + rk] = (short)k;
    }
    __syncthreads();
    for (int j = tid; j < m; j += 256) {
        int k = sidx[j];
        int i = i0 + k;
        int r = erow[i];
        int c = ecol[i];
        int b = r >> BSH;
        float t = f1[r] + f2[c];
        t = (t >= 0.f) ? t : LEAKY * t;
        float w = __expf(t);
        int dst = res[b] + (j - toff[b]);
        binned[dst] = make_int2(((r & (RBK - 1)) << 17) | c, __float_as_int(w));
        binw[dst] = 0.5f * adj[i] * w;
    }
}

// ---- SpMM over bucket-grouped edges; LDS fp32 accumulators; no CSR needed ----
// HOP 0: in=xh,  writes u1h + rs.   HOP 1: in=u1h, writes u2h.
// HOP 2: in=u2h, reads xh,g1h,rs -> out = 0.001x + 0.009*c0*g1 + 0.09*c1*g2 + 0.9*c2*g3
template<int HOP>
__global__ __launch_bounds__(512) void spmm_bucket(const __half2* __restrict__ upd_in,
                                                   __half2* __restrict__ upd_out,
                                                   const __half2* __restrict__ xh,
                                                   const __half2* __restrict__ g1h,
                                                   float* __restrict__ out,
                                                   const int2* __restrict__ binned,
                                                   const float* __restrict__ binw,
                                                   const int* __restrict__ bbase,
                                                   float* __restrict__ rsg,
                                                   const float* __restrict__ rs_in,
                                                   const float* __restrict__ cheb, int n) {
    int bk = blockIdx.x;
    int row0 = bk << BSH;
    int m0 = bbase[bk];
    int mend = bbase[bk + 1];
    int tid = threadIdx.x, wid = tid >> 6, lane = tid & 63;
    // even/odd feature split keeps LDS atomics conflict-free (lane-linear addresses)
    __shared__ float accx[RBK][64], accy[RBK][64], sl[RBK], rsl[RBK];
    for (int i = tid; i < RBK * 64; i += 512) { ((float*)accx)[i] = 0.f; ((float*)accy)[i] = 0.f; }
    if (tid < RBK) { sl[tid] = 0.f; rsl[tid] = 0.f; }
    __syncthreads();

    for (int base = m0 + wid * 64; base < mend; base += 512) {
        int idxe = base + lane;
        int2 ed = (idxe < mend) ? binned[idxe] : make_int2(0, 0);   // dummy: rl=0,c=0,w=0
        float bw = 0.f;
        if (HOP == 0) bw = (idxe < mend) ? binw[idxe] : 0.f;
        for (int j = 0; j < 64; j += 8) {
            __half2 g[8]; float u[8]; int rl8[8]; float bw8[8];
            #pragma unroll
            for (int k = 0; k < 8; k++) {
                int ex = __shfl(ed.x, j + k);
                int ey = __shfl(ed.y, j + k);
                rl8[k] = (ex >> 17) & (RBK - 1);
                int c = ex & CMASK;
                u[k] = __int_as_float(ey);
                g[k] = upd_in[(size_t)c * 64 + lane];
                if (HOP == 0) bw8[k] = __shfl(bw, j + k);
            }
            #pragma unroll
            for (int k = 0; k < 8; k++) {
                float2 f = __half22float2(g[k]);
                atomicAdd(&accx[rl8[k]][lane], u[k] * f.x);
                atomicAdd(&accy[rl8[k]][lane], u[k] * f.y);
                if (lane == 0) {
                    atomicAdd(&sl[rl8[k]], u[k]);
                    if (HOP == 0) atomicAdd(&rsl[rl8[k]], bw8[k]);
                }
            }
        }
    }
    __syncthreads();

    for (int r = wid; r < RBK; r += 8) {
        int gr = row0 + r;
        if (gr >= n) break;
        float s = sl[r];
        float inv = (s > 0.f) ? 1.f / s : 0.f;
        float gx = accx[r][lane] * inv;
        float gy = accy[r][lane] * inv;
        size_t idx = (size_t)gr * 64 + lane;
        if (HOP < 2) {
            upd_out[idx] = __float22half2_rn(make_float2(gx, gy));
            if (HOP == 0 && lane == 0) rsg[gr] = rsl[r];
        } else {
            float rsum = rs_in[gr] * inv;
            float s0 = 1.f / (1.f + __expf(-cheb[0]));
            float s1 = 1.f / (1.f + __expf(-cheb[1]));
            float c0 = 1.f - BETA * rsum;
            float c1 = 1.f - BETA * rsum * s0;
            float c2 = 1.f - BETA * rsum * s0 * s1;
            float2 xv = __half22float2(xh[idx]);
            float2 g1 = __half22float2(g1h[idx]);
            float2 g2 = __half22float2(upd_in[idx]);
            float2 o;
            o.x = 0.001f * xv.x + 0.009f * c0 * g1.x + 0.09f * c1 * g2.x + 0.9f * c2 * gx;
            o.y = 0.001f * xv.y + 0.009f * c0 * g1.y + 0.09f * c1 * g2.y + 0.9f * c2 * gy;
            ((float2*)out)[idx] = o;
        }
    }
}

extern "C" void kernel_launch(void* const* d_in, const int* in_sizes, int n_in,
                              void* d_out, int out_size, void* d_ws, size_t ws_size,
                              hipStream_t stream) {
    const float* x    = (const float*)d_in[0];
    const float* a    = (const float*)d_in[2];
    const float* cheb = (const float*)d_in[4];
    const float* adj  = (const float*)d_in[5];
    const int*   erow = (const int*)d_in[6];
    const int*   ecol = (const int*)d_in[7];
    int n = in_sizes[0] / F;
    int e = in_sizes[5];
    float* out = (float*)d_out;
    int nb = (n + RBK - 1) >> BSH;

    // workspace layout (4-byte words) — no aliasing
    float* ws = (float*)d_ws;
    size_t NH = (size_t)n * 64;               // half2 words per feature buffer
    int2*    binned = (int2*)ws;              // 2E words
    float*   binw   = ws + 2 * (size_t)e;     // E words
    __half2* xh   = (__half2*)(binw + e);
    __half2* u1h  = xh + NH;
    __half2* u2h  = u1h + NH;
    float* f1     = (float*)(u2h + NH);
    float* f2     = f1 + n;
    float* rs     = f2 + n;
    int*   bcnt   = (int*)(rs + n);           // nb (<=2048)
    int*   bbase  = bcnt + NBMAX;             // nb+1
    int*   bcur   = bbase + NBMAX + 1;        // nb+1

    int wave_blocks = (n + 3) / 4;

    hipLaunchKernelGGL(zero_ints, dim3(8), dim3(256), 0, stream, bcnt, nb);
    hipLaunchKernelGGL(featconv, dim3(wave_blocks), dim3(256), 0, stream, x, a, f1, f2, xh, n);
    hipLaunchKernelGGL(bucket_hist, dim3(1024), dim3(256), 0, stream, erow, bcnt, e, nb);
    hipLaunchKernelGGL(bucket_scan, dim3(1), dim3(1024), 0, stream, bcnt, bbase, bcur, nb);
    hipLaunchKernelGGL(bin_edges, dim3((e + BT - 1) / BT), dim3(256), 0, stream,
                       erow, ecol, adj, f1, f2, bcur, binned, binw, e);

    // hop 0: g1 = norm(U) @ xh ; writes rs
    hipLaunchKernelGGL((spmm_bucket<0>), dim3(nb), dim3(512), 0, stream,
                       xh, u1h, (const __half2*)nullptr, (const __half2*)nullptr,
                       (float*)nullptr, binned, binw, bbase, rs, (const float*)nullptr, cheb, n);
    // hop 1: g2 = norm(U) @ g1
    hipLaunchKernelGGL((spmm_bucket<1>), dim3(nb), dim3(512), 0, stream,
                       u1h, u2h, (const __half2*)nullptr, (const __half2*)nullptr,
                       (float*)nullptr, binned, (const float*)nullptr, bbase,
                       (float*)nullptr, (const float*)nullptr, cheb, n);
    // hop 2: g3 gather + fused final epilogue
    hipLaunchKernelGGL((spmm_bucket<2>), dim3(nb), dim3(512), 0, stream,
                       u2h, (__half2*)nullptr, xh, u1h,
                       out, binned, (const float*)nullptr, bbase,
                       (float*)nullptr, rs, cheb, n);
}

// Round 12
// 340.691 us; speedup vs baseline: 11.5689x; 11.5689x over previous
//
#include <hip/hip_runtime.h>
#include <hip/hip_fp16.h>

#define F 128
#define BETA  0.9f
#define LEAKY 0.2f

#define BSH 6          // rows per bucket = 64
#define RPB 64
#define NBMAX 2048     // max buckets (n <= 131072)
#define BT  2048       // edges per bin tile
#define CMASK 0x1FFFF

// ---- zero an int array ----
__global__ __launch_bounds__(256) void zero_ints(int* __restrict__ p, int n) {
    int i = blockIdx.x * 256 + threadIdx.x;
    int st = gridDim.x * 256;
    for (; i < n; i += st) p[i] = 0;
}

// ---- fused: f1/f2 projections + fp32->fp16 convert of x; one wave per row ----
__global__ __launch_bounds__(256) void featconv(const float* __restrict__ x,
                                                const float* __restrict__ a,
                                                float* __restrict__ f1,
                                                float* __restrict__ f2,
                                                __half2* __restrict__ xh, int n) {
    int w = (blockIdx.x * blockDim.x + threadIdx.x) >> 6;
    int lane = threadIdx.x & 63;
    if (w >= n) return;
    const float2* xr = (const float2*)(x + (size_t)w * F);
    float2 v  = xr[lane];
    float2 A1 = ((const float2*)a)[lane];
    float2 A2 = ((const float2*)a)[64 + lane];
    float d1 = v.x * A1.x + v.y * A1.y;
    float d2 = v.x * A2.x + v.y * A2.y;
    for (int o = 32; o; o >>= 1) {
        d1 += __shfl_xor(d1, o);
        d2 += __shfl_xor(d2, o);
    }
    xh[(size_t)w * 64 + lane] = __float22half2_rn(v);
    if (lane == 0) { f1[w] = d1; f2[w] = d2; }
}

// ---- per-bucket edge histogram (LDS-staged, up to 2048 buckets) ----
__global__ __launch_bounds__(256) void bucket_hist(const int* __restrict__ erow,
                                                   int* __restrict__ bcnt, int e, int nb) {
    __shared__ int h[NBMAX];
    for (int b = threadIdx.x; b < NBMAX; b += 256) h[b] = 0;
    __syncthreads();
    int i = blockIdx.x * 256 + threadIdx.x;
    int st = gridDim.x * 256;
    for (; i < e; i += st) atomicAdd(&h[erow[i] >> BSH], 1);
    __syncthreads();
    for (int b = threadIdx.x; b < nb; b += 256)
        if (h[b]) atomicAdd(&bcnt[b], h[b]);
}

// ---- scan bucket counts -> base & cursor (single block, 1024 threads, pair scan) ----
__global__ __launch_bounds__(1024) void bucket_scan(const int* __restrict__ bcnt,
                                                    int* __restrict__ base,
                                                    int* __restrict__ cursor,
                                                    int nb) {
    __shared__ int arr[1024];
    int t = threadIdx.x;
    int v0 = (2 * t     < nb) ? bcnt[2 * t]     : 0;
    int v1 = (2 * t + 1 < nb) ? bcnt[2 * t + 1] : 0;
    int ps = v0 + v1;
    arr[t] = ps; __syncthreads();
    for (int off = 1; off < 1024; off <<= 1) {
        int add = (t >= off) ? arr[t - off] : 0;
        __syncthreads();
        arr[t] += add;
        __syncthreads();
    }
    int ex = arr[t] - ps;
    if (2 * t     <= nb) { base[2 * t]     = ex;      cursor[2 * t]     = ex; }
    if (2 * t + 1 <= nb) { base[2 * t + 1] = ex + v0; cursor[2 * t + 1] = ex + v0; }
}

// ---- bin: write edges bucket-grouped (coalesced) as packed int2 (col|row_local, adj) ----
__global__ __launch_bounds__(256) void bin_edges(const int* __restrict__ erow,
                                                 const int* __restrict__ ecol,
                                                 const float* __restrict__ adj,
                                                 int* __restrict__ cursor,
                                                 int2* __restrict__ binned, int e) {
    __shared__ int tcnt[NBMAX], toff[NBMAX], res[NBMAX], tcur[NBMAX];
    __shared__ int arr[256];
    __shared__ short sidx[BT];
    int tid = threadIdx.x;
    int i0 = blockIdx.x * BT;
    int m = e - i0; if (m > BT) m = BT;
    for (int b = tid; b < NBMAX; b += 256) tcnt[b] = 0;
    __syncthreads();
    for (int k = tid; k < m; k += 256) atomicAdd(&tcnt[erow[i0 + k] >> BSH], 1);
    __syncthreads();
    // scan tcnt[2048] -> toff: 8 consecutive per thread + HS over 256
    int loc[8]; int s8 = 0; int b8 = tid * 8;
    #pragma unroll
    for (int k = 0; k < 8; k++) { loc[k] = tcnt[b8 + k]; s8 += loc[k]; }
    arr[tid] = s8; __syncthreads();
    for (int off = 1; off < 256; off <<= 1) {
        int add = (tid >= off) ? arr[tid - off] : 0;
        __syncthreads();
        arr[tid] += add;
        __syncthreads();
    }
    int ex = arr[tid] - s8;
    #pragma unroll
    for (int k = 0; k < 8; k++) { toff[b8 + k] = ex; ex += loc[k]; }
    __syncthreads();
    for (int b = tid; b < NBMAX; b += 256) {
        if (tcnt[b] > 0) res[b] = atomicAdd(&cursor[b], tcnt[b]);
        tcur[b] = 0;
    }
    __syncthreads();
    for (int k = tid; k < m; k += 256) {
        int b = erow[i0 + k] >> BSH;
        int rk = atomicAdd(&tcur[b], 1);
        sidx[toff[b] + rk] = (short)k;
    }
    __syncthreads();
    for (int j = tid; j < m; j += 256) {
        int k = sidx[j];
        int i = i0 + k;
        int r = erow[i];
        int b = r >> BSH;
        int dst = res[b] + (j - toff[b]);
        binned[dst] = make_int2(((r & (RPB - 1)) << 17) | ecol[i], __float_as_int(adj[i]));
    }
}

// ---- build: per-bucket row-sort; CSR written DIRECTLY (bucket range is L2-local) ----
__global__ __launch_bounds__(256) void build_csr(const int2* __restrict__ binned,
                                                 const int* __restrict__ bbase,
                                                 const float* __restrict__ f1,
                                                 const float* __restrict__ f2,
                                                 int2* __restrict__ csr,
                                                 int* __restrict__ rowptr,
                                                 float* __restrict__ sden,
                                                 float* __restrict__ rsg, int n) {
    int k = blockIdx.x;
    int row0 = k << BSH;
    int nr = n - row0; if (nr > RPB) nr = RPB;
    int m0 = bbase[k];
    int m = bbase[k + 1] - m0;
    int tid = threadIdx.x;
    __shared__ int   cnt[RPB], cur[RPB], rpl[RPB];
    __shared__ float f1l[RPB], sl[RPB], rsl[RPB];
    if (tid < RPB) {
        cnt[tid] = 0; cur[tid] = 0; sl[tid] = 0.f; rsl[tid] = 0.f;
        f1l[tid] = (tid < nr) ? f1[row0 + tid] : 0.f;
    }
    __syncthreads();
    for (int t = tid; t < m; t += 256) atomicAdd(&cnt[(binned[m0 + t].x >> 17) & (RPB - 1)], 1);
    __syncthreads();
    // exclusive scan of cnt[64] using threads 0..63 (HS in LDS)
    if (tid < RPB) rpl[tid] = cnt[tid];
    __syncthreads();
    for (int off = 1; off < RPB; off <<= 1) {
        int add = 0;
        if (tid < RPB && tid >= off) add = rpl[tid - off];
        __syncthreads();
        if (tid < RPB) rpl[tid] += add;
        __syncthreads();
    }
    if (tid < RPB) rpl[tid] -= cnt[tid];          // exclusive
    __syncthreads();
    if (tid < nr) rowptr[row0 + tid] = m0 + rpl[tid];
    // place edges: compute exp, write csr directly, accumulate s/rs in LDS
    for (int t = tid; t < m; t += 256) {
        int2 w = binned[m0 + t];
        int rl = (w.x >> 17) & (RPB - 1);
        int c  = w.x & CMASK;
        float tt = f1l[rl] + f2[c];
        tt = (tt >= 0.f) ? tt : LEAKY * tt;
        float exv = __expf(tt);
        int pos = atomicAdd(&cur[rl], 1);
        csr[m0 + rpl[rl] + pos] = make_int2(c, __float_as_int(exv));
        atomicAdd(&sl[rl], exv);
        atomicAdd(&rsl[rl], 0.5f * __int_as_float(w.y) * exv);
    }
    __syncthreads();
    if (tid < nr) { sden[row0 + tid] = sl[tid]; rsg[row0 + tid] = rsl[tid]; }
}

// ---- SpMM hop (fp16 gather, 8-deep batched); one wave per row ----
// final_hop == 0: writes g = acc/s as fp16 only.
// final_hop != 0: out = 0.001*x + 0.009*c0*g1 + 0.09*c1*g2 + 0.9*c2*g3
__global__ __launch_bounds__(256) void spmm_fuse(const __half2* __restrict__ upd_in,
                                                 __half2* __restrict__ upd_out,
                                                 const __half2* __restrict__ xh,
                                                 const __half2* __restrict__ g1h,
                                                 float* __restrict__ out,
                                                 const int2* __restrict__ csr,
                                                 const int* __restrict__ rowptr,
                                                 const float* __restrict__ sden,
                                                 const float* __restrict__ rs,
                                                 const float* __restrict__ cheb,
                                                 int n, int final_hop) {
    int r = blockIdx.x * 4 + (threadIdx.x >> 6);
    int lane = threadIdx.x & 63;
    if (r >= n) return;
    int sp = rowptr[r];
    int deg = rowptr[r + 1] - sp;

    float2 acc = make_float2(0.f, 0.f);
    for (int base = 0; base < deg; base += 64) {
        int mm = deg - base; if (mm > 64) mm = 64;
        int2 ed = (lane < mm) ? csr[sp + base + lane] : make_int2(0, 0);
        int mm8 = (mm + 7) & ~7;
        for (int j = 0; j < mm8; j += 8) {
            float2 g[8]; float u[8];
            #pragma unroll
            for (int kk = 0; kk < 8; kk++) {
                int c  = __shfl(ed.x, j + kk) & CMASK;
                u[kk]  = __int_as_float(__shfl(ed.y, j + kk));
                g[kk]  = __half22float2(upd_in[(size_t)c * 64 + lane]);
            }
            #pragma unroll
            for (int kk = 0; kk < 8; kk++) {
                acc.x += u[kk] * g[kk].x;
                acc.y += u[kk] * g[kk].y;
            }
        }
    }

    float sr = sden[r];
    float inv = (sr > 0.f) ? 1.f / sr : 0.f;
    float gx = acc.x * inv, gy = acc.y * inv;
    size_t idx = (size_t)r * 64 + lane;

    if (!final_hop) {
        upd_out[idx] = __float22half2_rn(make_float2(gx, gy));
    } else {
        float rsum = rs[r] * inv;
        float s0 = 1.f / (1.f + __expf(-cheb[0]));
        float s1 = 1.f / (1.f + __expf(-cheb[1]));
        float c0 = 1.f - BETA * rsum;
        float c1 = 1.f - BETA * rsum * s0;
        float c2 = 1.f - BETA * rsum * s0 * s1;
        float2 xv = __half22float2(xh[idx]);
        float2 g1 = __half22float2(g1h[idx]);
        float2 g2 = __half22float2(upd_in[idx]);
        float2 o;
        o.x = 0.001f * xv.x + 0.009f * c0 * g1.x + 0.09f * c1 * g2.x + 0.9f * c2 * gx;
        o.y = 0.001f * xv.y + 0.009f * c0 * g1.y + 0.09f * c1 * g2.y + 0.9f * c2 * gy;
        ((float2*)out)[idx] = o;
    }
}

extern "C" void kernel_launch(void* const* d_in, const int* in_sizes, int n_in,
                              void* d_out, int out_size, void* d_ws, size_t ws_size,
                              hipStream_t stream) {
    const float* x    = (const float*)d_in[0];
    const float* a    = (const float*)d_in[2];
    const float* cheb = (const float*)d_in[4];
    const float* adj  = (const float*)d_in[5];
    const int*   erow = (const int*)d_in[6];
    const int*   ecol = (const int*)d_in[7];
    int n = in_sizes[0] / F;
    int e = in_sizes[5];
    float* out = (float*)d_out;
    int nb = (n + RPB - 1) >> BSH;

    // workspace layout (4-byte words); only alias: binned -> u2h (dead before hop1 writes u2h)
    float* ws = (float*)d_ws;
    size_t NH = (size_t)n * 64;               // half2 words per feature buffer
    int2*    csr  = (int2*)ws;                // 2E words
    __half2* xh   = (__half2*)(ws + 2 * (size_t)e);
    __half2* u1h  = xh + NH;
    __half2* u2h  = u1h + NH;
    int2*    binned = (int2*)u2h;             // E int2, dead after build_csr
    float* f1     = (float*)(u2h + NH);
    float* f2     = f1 + n;
    float* sden   = f2 + n;
    float* rs     = sden + n;
    int*   rowptr = (int*)(rs + n);           // n+1
    int*   bcnt   = rowptr + n + 1;           // nb (<=2048)
    int*   bbase  = bcnt + NBMAX;             // nb+1
    int*   bcur   = bbase + NBMAX + 1;        // nb+1

    int wave_blocks = (n + 3) / 4;

    hipLaunchKernelGGL(zero_ints, dim3(8), dim3(256), 0, stream, bcnt, nb);
    hipLaunchKernelGGL(featconv, dim3(wave_blocks), dim3(256), 0, stream, x, a, f1, f2, xh, n);
    hipLaunchKernelGGL(bucket_hist, dim3(1024), dim3(256), 0, stream, erow, bcnt, e, nb);
    hipLaunchKernelGGL(bucket_scan, dim3(1), dim3(1024), 0, stream, bcnt, bbase, bcur, nb);
    hipLaunchKernelGGL(bin_edges, dim3((e + BT - 1) / BT), dim3(256), 0, stream,
                       erow, ecol, adj, bcur, binned, e);
    hipLaunchKernelGGL(build_csr, dim3(nb), dim3(256), 0, stream,
                       binned, bbase, f1, f2, csr, rowptr, sden, rs, n);
    // rowptr[n] = e (sentinel for last row's degree)
    hipMemcpyAsync(rowptr + n, bbase + nb, sizeof(int), hipMemcpyDeviceToDevice, stream);

    // hop 0: g1 = norm(U) @ xh              (final_hop = 0)
    hipLaunchKernelGGL(spmm_fuse, dim3(wave_blocks), dim3(256), 0, stream,
                       xh, u1h, (const __half2*)nullptr, (const __half2*)nullptr,
                       (float*)nullptr, csr, rowptr, sden, rs, cheb, n, 0);
    // hop 1: g2 = norm(U) @ g1              (final_hop = 0)
    hipLaunchKernelGGL(spmm_fuse, dim3(wave_blocks), dim3(256), 0, stream,
                       u1h, u2h, (const __half2*)nullptr, (const __half2*)nullptr,
                       (float*)nullptr, csr, rowptr, sden, rs, cheb, n, 0);
    // hop 2: g3 gather + fused final epilogue (final_hop = 1)
    hipLaunchKernelGGL(spmm_fuse, dim3(wave_blocks), dim3(256), 0, stream,
                       u2h, (__half2*)nullptr, xh, u1h,
                       out, csr, rowptr, sden, rs, cheb, n, 1);
}

// Round 13
// 309.871 us; speedup vs baseline: 12.7196x; 1.0995x over previous
//
#include <hip/hip_runtime.h>
#include <hip/hip_fp16.h>

#define F 128
#define BETA  0.9f
#define LEAKY 0.2f

#define RSH 8          // rows per bucket = 256
#define RB  256
#define BT  4096       // edges per bin tile
#define CMASK 0x1FFFF

// ---- zero an int array ----
__global__ __launch_bounds__(256) void zero_ints(int* __restrict__ p, int n) {
    int i = blockIdx.x * 256 + threadIdx.x;
    int st = gridDim.x * 256;
    for (; i < n; i += st) p[i] = 0;
}

// ---- fused: f1/f2 projections + fp32->fp16 convert of x; one wave per row ----
__global__ __launch_bounds__(256) void featconv(const float* __restrict__ x,
                                                const float* __restrict__ a,
                                                float* __restrict__ f1,
                                                float* __restrict__ f2,
                                                __half2* __restrict__ xh, int n) {
    int w = (blockIdx.x * blockDim.x + threadIdx.x) >> 6;
    int lane = threadIdx.x & 63;
    if (w >= n) return;
    const float2* xr = (const float2*)(x + (size_t)w * F);
    float2 v  = xr[lane];
    float2 A1 = ((const float2*)a)[lane];
    float2 A2 = ((const float2*)a)[64 + lane];
    float d1 = v.x * A1.x + v.y * A1.y;
    float d2 = v.x * A2.x + v.y * A2.y;
    for (int o = 32; o; o >>= 1) {
        d1 += __shfl_xor(d1, o);
        d2 += __shfl_xor(d2, o);
    }
    xh[(size_t)w * 64 + lane] = __float22half2_rn(v);
    if (lane == 0) { f1[w] = d1; f2[w] = d2; }
}

// ---- per-bucket edge histogram (LDS-staged) ----
__global__ __launch_bounds__(256) void bucket_hist(const int* __restrict__ erow,
                                                   int* __restrict__ bcnt, int e, int nb) {
    __shared__ int h[512];
    h[threadIdx.x] = 0; h[256 + threadIdx.x] = 0;
    __syncthreads();
    int i = blockIdx.x * 256 + threadIdx.x;
    int st = gridDim.x * 256;
    for (; i < e; i += st) atomicAdd(&h[erow[i] >> RSH], 1);
    __syncthreads();
    for (int b = threadIdx.x; b < nb; b += 256)
        if (h[b]) atomicAdd(&bcnt[b], h[b]);
}

// ---- scan bucket counts -> base & cursor (single block, pair Hillis-Steele) ----
__global__ __launch_bounds__(256) void bucket_scan(const int* __restrict__ bcnt,
                                                   int* __restrict__ base,
                                                   int* __restrict__ cursor,
                                                   int* __restrict__ rowptr_n,
                                                   int nb, int e) {
    __shared__ int arr[256];
    int t = threadIdx.x;
    int v0 = (2 * t     < nb) ? bcnt[2 * t]     : 0;
    int v1 = (2 * t + 1 < nb) ? bcnt[2 * t + 1] : 0;
    int ps = v0 + v1;
    arr[t] = ps; __syncthreads();
    for (int off = 1; off < 256; off <<= 1) {
        int add = (t >= off) ? arr[t - off] : 0;
        __syncthreads();
        arr[t] += add;
        __syncthreads();
    }
    int ex = arr[t] - ps;
    if (2 * t     <= nb) { base[2 * t]     = ex;      cursor[2 * t]     = ex; }
    if (2 * t + 1 <= nb) { base[2 * t + 1] = ex + v0; cursor[2 * t + 1] = ex + v0; }
    if (t == 255) *rowptr_n = e;
}

// ---- bin: write edges bucket-grouped (coalesced) as packed int2 ----
__global__ __launch_bounds__(256) void bin_edges(const int* __restrict__ erow,
                                                 const int* __restrict__ ecol,
                                                 const float* __restrict__ adj,
                                                 int* __restrict__ cursor,
                                                 int2* __restrict__ binned, int e) {
    __shared__ int tcnt[512], toff[512], res[512], tcur[512];
    __shared__ int arr[256];
    __shared__ short sidx[BT];
    int tid = threadIdx.x;
    int i0 = blockIdx.x * BT;
    int m = e - i0; if (m > BT) m = BT;
    tcnt[tid] = 0; tcnt[256 + tid] = 0;
    __syncthreads();
    for (int k = tid; k < m; k += 256) atomicAdd(&tcnt[erow[i0 + k] >> RSH], 1);
    __syncthreads();
    int v0 = tcnt[2 * tid], v1 = tcnt[2 * tid + 1];
    int ps = v0 + v1;
    arr[tid] = ps; __syncthreads();
    for (int off = 1; off < 256; off <<= 1) {
        int add = (tid >= off) ? arr[tid - off] : 0;
        __syncthreads();
        arr[tid] += add;
        __syncthreads();
    }
    int ex = arr[tid] - ps;
    toff[2 * tid] = ex; toff[2 * tid + 1] = ex + v0;
    __syncthreads();
    for (int b = tid; b < 512; b += 256) {
        if (tcnt[b] > 0) res[b] = atomicAdd(&cursor[b], tcnt[b]);
        tcur[b] = 0;
    }
    __syncthreads();
    for (int k = tid; k < m; k += 256) {
        int b = erow[i0 + k] >> RSH;
        int rk = atomicAdd(&tcur[b], 1);
        sidx[toff[b] + rk] = (short)k;
    }
    __syncthreads();
    for (int j = tid; j < m; j += 256) {
        int k = sidx[j];
        int i = i0 + k;
        int r = erow[i];
        int b = r >> RSH;
        int dst = res[b] + (j - toff[b]);
        binned[dst] = make_int2(((r & (RB - 1)) << 17) | ecol[i], __float_as_int(adj[i]));
    }
}

// ---- build: per-bucket row-sort; CSR written directly (bucket segment is L2-local) ----
__global__ __launch_bounds__(256) void build_csr(const int2* __restrict__ binned,
                                                 const int* __restrict__ bbase,
                                                 const float* __restrict__ f1,
                                                 const float* __restrict__ f2,
                                                 int2* __restrict__ csr,
                                                 int* __restrict__ rowptr,
                                                 float* __restrict__ sden,
                                                 float* __restrict__ rsg, int n) {
    int k = blockIdx.x;
    int row0 = k << RSH;
    int nr = n - row0; if (nr > RB) nr = RB;
    int m0 = bbase[k];
    int m = bbase[k + 1] - m0;
    int tid = threadIdx.x;
    __shared__ int   cnt[RB], cur[RB], rpl[RB], arr[256];
    __shared__ float f1l[RB], sl[RB], rsl[RB];
    cnt[tid] = 0; cur[tid] = 0; sl[tid] = 0.f; rsl[tid] = 0.f;
    f1l[tid] = (tid < nr) ? f1[row0 + tid] : 0.f;
    __syncthreads();
    for (int t = tid; t < m; t += 256) atomicAdd(&cnt[(binned[m0 + t].x >> 17) & 0xFF], 1);
    __syncthreads();
    int v = cnt[tid];
    arr[tid] = v; __syncthreads();
    for (int off = 1; off < 256; off <<= 1) {
        int add = (tid >= off) ? arr[tid - off] : 0;
        __syncthreads();
        arr[tid] += add;
        __syncthreads();
    }
    rpl[tid] = arr[tid] - v;
    __syncthreads();
    if (tid < nr) rowptr[row0 + tid] = m0 + rpl[tid];
    // place edges: exp + direct CSR write (scattered within this bucket's ~32KB segment)
    for (int t = tid; t < m; t += 256) {
        int2 w = binned[m0 + t];
        int rl = (w.x >> 17) & 0xFF;
        int c  = w.x & CMASK;
        float tt = f1l[rl] + f2[c];
        tt = (tt >= 0.f) ? tt : LEAKY * tt;
        float exv = __expf(tt);
        int pos = atomicAdd(&cur[rl], 1);
        csr[m0 + rpl[rl] + pos] = make_int2(c, __float_as_int(exv));
        atomicAdd(&sl[rl], exv);
        atomicAdd(&rsl[rl], 0.5f * __int_as_float(w.y) * exv);
    }
    __syncthreads();
    if (tid < nr) { sden[row0 + tid] = sl[tid]; rsg[row0 + tid] = rsl[tid]; }
}

// ---- SpMM hop (fp16 gather, 8-deep batched); one wave per row ----
// final_hop == 0: writes g = acc/s as fp16 only.
// final_hop != 0: out = 0.001*x + 0.009*c0*g1 + 0.09*c1*g2 + 0.9*c2*g3
__global__ __launch_bounds__(256) void spmm_fuse(const __half2* __restrict__ upd_in,
                                                 __half2* __restrict__ upd_out,
                                                 const __half2* __restrict__ xh,
                                                 const __half2* __restrict__ g1h,
                                                 float* __restrict__ out,
                                                 const int2* __restrict__ csr,
                                                 const int* __restrict__ rowptr,
                                                 const float* __restrict__ sden,
                                                 const float* __restrict__ rs,
                                                 const float* __restrict__ cheb,
                                                 int n, int final_hop) {
    int r = blockIdx.x * 4 + (threadIdx.x >> 6);
    int lane = threadIdx.x & 63;
    if (r >= n) return;
    int sp = rowptr[r];
    int deg = rowptr[r + 1] - sp;

    float2 acc = make_float2(0.f, 0.f);
    for (int base = 0; base < deg; base += 64) {
        int mm = deg - base; if (mm > 64) mm = 64;
        int2 ed = (lane < mm) ? csr[sp + base + lane] : make_int2(0, 0);
        int mm8 = (mm + 7) & ~7;
        for (int j = 0; j < mm8; j += 8) {
            float2 g[8]; float u[8];
            #pragma unroll
            for (int kk = 0; kk < 8; kk++) {
                int c  = __shfl(ed.x, j + kk) & CMASK;
                u[kk]  = __int_as_float(__shfl(ed.y, j + kk));
                g[kk]  = __half22float2(upd_in[(size_t)c * 64 + lane]);
            }
            #pragma unroll
            for (int kk = 0; kk < 8; kk++) {
                acc.x += u[kk] * g[kk].x;
                acc.y += u[kk] * g[kk].y;
            }
        }
    }

    float sr = sden[r];
    float inv = (sr > 0.f) ? 1.f / sr : 0.f;
    float gx = acc.x * inv, gy = acc.y * inv;
    size_t idx = (size_t)r * 64 + lane;

    if (!final_hop) {
        upd_out[idx] = __float22half2_rn(make_float2(gx, gy));
    } else {
        float rsum = rs[r] * inv;
        float s0 = 1.f / (1.f + __expf(-cheb[0]));
        float s1 = 1.f / (1.f + __expf(-cheb[1]));
        float c0 = 1.f - BETA * rsum;
        float c1 = 1.f - BETA * rsum * s0;
        float c2 = 1.f - BETA * rsum * s0 * s1;
        float2 xv = __half22float2(xh[idx]);
        float2 g1 = __half22float2(g1h[idx]);
        float2 g2 = __half22float2(upd_in[idx]);
        float2 o;
        o.x = 0.001f * xv.x + 0.009f * c0 * g1.x + 0.09f * c1 * g2.x + 0.9f * c2 * gx;
        o.y = 0.001f * xv.y + 0.009f * c0 * g1.y + 0.09f * c1 * g2.y + 0.9f * c2 * gy;
        ((float2*)out)[idx] = o;
    }
}

extern "C" void kernel_launch(void* const* d_in, const int* in_sizes, int n_in,
                              void* d_out, int out_size, void* d_ws, size_t ws_size,
                              hipStream_t stream) {
    const float* x    = (const float*)d_in[0];
    const float* a    = (const float*)d_in[2];
    const float* cheb = (const float*)d_in[4];
    const float* adj  = (const float*)d_in[5];
    const int*   erow = (const int*)d_in[6];
    const int*   ecol = (const int*)d_in[7];
    int n = in_sizes[0] / F;
    int e = in_sizes[5];
    float* out = (float*)d_out;
    int nb = (n + RB - 1) >> RSH;

    // workspace layout (4-byte words); only alias: binned -> u2h (dead before hop1 writes u2h)
    float* ws = (float*)d_ws;
    size_t NH = (size_t)n * 64;               // half2 words per feature buffer
    int2*    csr  = (int2*)ws;                // 2E words
    __half2* xh   = (__half2*)(ws + 2 * (size_t)e);
    __half2* u1h  = xh + NH;
    __half2* u2h  = u1h + NH;
    int2*    binned = (int2*)u2h;             // E int2, dead after build_csr
    float* f1     = (float*)(u2h + NH);
    float* f2     = f1 + n;
    float* sden   = f2 + n;
    float* rs     = sden + n;
    int*   rowptr = (int*)(rs + n);           // n+1
    int*   bcnt   = rowptr + n + 1;           // nb (<=512)
    int*   bbase  = bcnt + 512;               // nb+1
    int*   bcur   = bbase + 513;              // nb+1

    int wave_blocks = (n + 3) / 4;

    hipLaunchKernelGGL(zero_ints, dim3(4), dim3(256), 0, stream, bcnt, nb);
    hipLaunchKernelGGL(featconv, dim3(wave_blocks), dim3(256), 0, stream, x, a, f1, f2, xh, n);
    hipLaunchKernelGGL(bucket_hist, dim3(1024), dim3(256), 0, stream, erow, bcnt, e, nb);
    hipLaunchKernelGGL(bucket_scan, dim3(1), dim3(256), 0, stream, bcnt, bbase, bcur, rowptr + n, nb, e);
    hipLaunchKernelGGL(bin_edges, dim3((e + BT - 1) / BT), dim3(256), 0, stream,
                       erow, ecol, adj, bcur, binned, e);
    hipLaunchKernelGGL(build_csr, dim3(nb), dim3(256), 0, stream,
                       binned, bbase, f1, f2, csr, rowptr, sden, rs, n);

    // hop 0: g1 = norm(U) @ xh              (final_hop = 0)
    hipLaunchKernelGGL(spmm_fuse, dim3(wave_blocks), dim3(256), 0, stream,
                       xh, u1h, (const __half2*)nullptr, (const __half2*)nullptr,
                       (float*)nullptr, csr, rowptr, sden, rs, cheb, n, 0);
    // hop 1: g2 = norm(U) @ g1              (final_hop = 0)
    hipLaunchKernelGGL(spmm_fuse, dim3(wave_blocks), dim3(256), 0, stream,
                       u1h, u2h, (const __half2*)nullptr, (const __half2*)nullptr,
                       (float*)nullptr, csr, rowptr, sden, rs, cheb, n, 0);
    // hop 2: g3 gather + fused final epilogue (final_hop = 1)
    hipLaunchKernelGGL(spmm_fuse, dim3(wave_blocks), dim3(256), 0, stream,
                       u2h, (__half2*)nullptr, xh, u1h,
                       out, csr, rowptr, sden, rs, cheb, n, 1);
}

// Round 14
// 308.862 us; speedup vs baseline: 12.7611x; 1.0033x over previous
//
#include <hip/hip_runtime.h>
#include <hip/hip_fp16.h>

#define F 128
#define BETA  0.9f
#define LEAKY 0.2f

#define RSH 8          // rows per bucket = 256
#define RB  256
#define BT  4096       // edges per bin tile
#define CMASK 0x1FFFF
#define HG  1024       // blocks participating in fused histogram

// ---- fused: f1/f2 projections + fp32->fp16 convert of x + bucket histogram ----
// one wave per row; blocks < HG additionally histogram edges (LDS-staged)
__global__ __launch_bounds__(256) void featconv_hist(const float* __restrict__ x,
                                                     const float* __restrict__ a,
                                                     float* __restrict__ f1,
                                                     float* __restrict__ f2,
                                                     __half2* __restrict__ xh, int n,
                                                     const int* __restrict__ erow,
                                                     int* __restrict__ bcnt, int e, int nb) {
    __shared__ int h[512];
    int tid = threadIdx.x;
    int w = (blockIdx.x * blockDim.x + tid) >> 6;
    int lane = tid & 63;
    if (w < n) {                                   // wave-uniform predicate
        const float2* xr = (const float2*)(x + (size_t)w * F);
        float2 v  = xr[lane];
        float2 A1 = ((const float2*)a)[lane];
        float2 A2 = ((const float2*)a)[64 + lane];
        float d1 = v.x * A1.x + v.y * A1.y;
        float d2 = v.x * A2.x + v.y * A2.y;
        for (int o = 32; o; o >>= 1) {
            d1 += __shfl_xor(d1, o);
            d2 += __shfl_xor(d2, o);
        }
        xh[(size_t)w * 64 + lane] = __float22half2_rn(v);
        if (lane == 0) { f1[w] = d1; f2[w] = d2; }
    }
    if (blockIdx.x < HG) {                         // block-uniform: syncthreads safe
        h[tid] = 0; h[256 + tid] = 0;
        __syncthreads();
        for (int i = blockIdx.x * 256 + tid; i < e; i += HG * 256)
            atomicAdd(&h[erow[i] >> RSH], 1);
        __syncthreads();
        for (int b = tid; b < nb; b += 256)
            if (h[b]) atomicAdd(&bcnt[b], h[b]);
    }
}

// ---- scan bucket counts -> base & cursor (single block, pair Hillis-Steele) ----
__global__ __launch_bounds__(256) void bucket_scan(const int* __restrict__ bcnt,
                                                   int* __restrict__ base,
                                                   int* __restrict__ cursor,
                                                   int* __restrict__ rowptr_n,
                                                   int nb, int e) {
    __shared__ int arr[256];
    int t = threadIdx.x;
    int v0 = (2 * t     < nb) ? bcnt[2 * t]     : 0;
    int v1 = (2 * t + 1 < nb) ? bcnt[2 * t + 1] : 0;
    int ps = v0 + v1;
    arr[t] = ps; __syncthreads();
    for (int off = 1; off < 256; off <<= 1) {
        int add = (t >= off) ? arr[t - off] : 0;
        __syncthreads();
        arr[t] += add;
        __syncthreads();
    }
    int ex = arr[t] - ps;
    if (2 * t     <= nb) { base[2 * t]     = ex;      cursor[2 * t]     = ex; }
    if (2 * t + 1 <= nb) { base[2 * t + 1] = ex + v0; cursor[2 * t + 1] = ex + v0; }
    if (t == 255) *rowptr_n = e;
}

// ---- bin: write edges bucket-grouped (coalesced) as packed int2 ----
__global__ __launch_bounds__(256) void bin_edges(const int* __restrict__ erow,
                                                 const int* __restrict__ ecol,
                                                 const float* __restrict__ adj,
                                                 int* __restrict__ cursor,
                                                 int2* __restrict__ binned, int e) {
    __shared__ int tcnt[512], toff[512], res[512], tcur[512];
    __shared__ int arr[256];
    __shared__ short sidx[BT];
    int tid = threadIdx.x;
    int i0 = blockIdx.x * BT;
    int m = e - i0; if (m > BT) m = BT;
    tcnt[tid] = 0; tcnt[256 + tid] = 0;
    __syncthreads();
    for (int k = tid; k < m; k += 256) atomicAdd(&tcnt[erow[i0 + k] >> RSH], 1);
    __syncthreads();
    int v0 = tcnt[2 * tid], v1 = tcnt[2 * tid + 1];
    int ps = v0 + v1;
    arr[tid] = ps; __syncthreads();
    for (int off = 1; off < 256; off <<= 1) {
        int add = (tid >= off) ? arr[tid - off] : 0;
        __syncthreads();
        arr[tid] += add;
        __syncthreads();
    }
    int ex = arr[tid] - ps;
    toff[2 * tid] = ex; toff[2 * tid + 1] = ex + v0;
    __syncthreads();
    for (int b = tid; b < 512; b += 256) {
        if (tcnt[b] > 0) res[b] = atomicAdd(&cursor[b], tcnt[b]);
        tcur[b] = 0;
    }
    __syncthreads();
    for (int k = tid; k < m; k += 256) {
        int b = erow[i0 + k] >> RSH;
        int rk = atomicAdd(&tcur[b], 1);
        sidx[toff[b] + rk] = (short)k;
    }
    __syncthreads();
    for (int j = tid; j < m; j += 256) {
        int k = sidx[j];
        int i = i0 + k;
        int r = erow[i];
        int b = r >> RSH;
        int dst = res[b] + (j - toff[b]);
        binned[dst] = make_int2(((r & (RB - 1)) << 17) | ecol[i], __float_as_int(adj[i]));
    }
}

// ---- build: per-bucket row-sort; CSR written directly (bucket segment is L2-local) ----
__global__ __launch_bounds__(256) void build_csr(const int2* __restrict__ binned,
                                                 const int* __restrict__ bbase,
                                                 const float* __restrict__ f1,
                                                 const float* __restrict__ f2,
                                                 int2* __restrict__ csr,
                                                 int* __restrict__ rowptr,
                                                 float* __restrict__ sden,
                                                 float* __restrict__ rsg, int n) {
    int k = blockIdx.x;
    int row0 = k << RSH;
    int nr = n - row0; if (nr > RB) nr = RB;
    int m0 = bbase[k];
    int m = bbase[k + 1] - m0;
    int tid = threadIdx.x;
    __shared__ int   cnt[RB], cur[RB], rpl[RB], arr[256];
    __shared__ float f1l[RB], sl[RB], rsl[RB];
    cnt[tid] = 0; cur[tid] = 0; sl[tid] = 0.f; rsl[tid] = 0.f;
    f1l[tid] = (tid < nr) ? f1[row0 + tid] : 0.f;
    __syncthreads();
    for (int t = tid; t < m; t += 256) atomicAdd(&cnt[(binned[m0 + t].x >> 17) & 0xFF], 1);
    __syncthreads();
    int v = cnt[tid];
    arr[tid] = v; __syncthreads();
    for (int off = 1; off < 256; off <<= 1) {
        int add = (tid >= off) ? arr[tid - off] : 0;
        __syncthreads();
        arr[tid] += add;
        __syncthreads();
    }
    rpl[tid] = arr[tid] - v;
    __syncthreads();
    if (tid < nr) rowptr[row0 + tid] = m0 + rpl[tid];
    for (int t = tid; t < m; t += 256) {
        int2 w = binned[m0 + t];
        int rl = (w.x >> 17) & 0xFF;
        int c  = w.x & CMASK;
        float tt = f1l[rl] + f2[c];
        tt = (tt >= 0.f) ? tt : LEAKY * tt;
        float exv = __expf(tt);
        int pos = atomicAdd(&cur[rl], 1);
        csr[m0 + rpl[rl] + pos] = make_int2(c, __float_as_int(exv));
        atomicAdd(&sl[rl], exv);
        atomicAdd(&rsl[rl], 0.5f * __int_as_float(w.y) * exv);
    }
    __syncthreads();
    if (tid < nr) { sden[row0 + tid] = sl[tid]; rsg[row0 + tid] = rsl[tid]; }
}

// ---- SpMM hop (fp16 gather, 8-deep batched); one wave per row ----
// final_hop == 0: writes g = acc/s as fp16 only.
// final_hop != 0: out = 0.001*x + 0.009*c0*g1 + 0.09*c1*g2 + 0.9*c2*g3
__global__ __launch_bounds__(256) void spmm_fuse(const __half2* __restrict__ upd_in,
                                                 __half2* __restrict__ upd_out,
                                                 const __half2* __restrict__ xh,
                                                 const __half2* __restrict__ g1h,
                                                 float* __restrict__ out,
                                                 const int2* __restrict__ csr,
                                                 const int* __restrict__ rowptr,
                                                 const float* __restrict__ sden,
                                                 const float* __restrict__ rs,
                                                 const float* __restrict__ cheb,
                                                 int n, int final_hop) {
    int r = blockIdx.x * 4 + (threadIdx.x >> 6);
    int lane = threadIdx.x & 63;
    if (r >= n) return;
    int sp = rowptr[r];
    int deg = rowptr[r + 1] - sp;

    float2 acc = make_float2(0.f, 0.f);
    for (int base = 0; base < deg; base += 64) {
        int mm = deg - base; if (mm > 64) mm = 64;
        int2 ed = (lane < mm) ? csr[sp + base + lane] : make_int2(0, 0);
        int mm8 = (mm + 7) & ~7;
        for (int j = 0; j < mm8; j += 8) {
            float2 g[8]; float u[8];
            #pragma unroll
            for (int kk = 0; kk < 8; kk++) {
                int c  = __shfl(ed.x, j + kk) & CMASK;
                u[kk]  = __int_as_float(__shfl(ed.y, j + kk));
                g[kk]  = __half22float2(upd_in[(size_t)c * 64 + lane]);
            }
            #pragma unroll
            for (int kk = 0; kk < 8; kk++) {
                acc.x += u[kk] * g[kk].x;
                acc.y += u[kk] * g[kk].y;
            }
        }
    }

    float sr = sden[r];
    float inv = (sr > 0.f) ? 1.f / sr : 0.f;
    float gx = acc.x * inv, gy = acc.y * inv;
    size_t idx = (size_t)r * 64 + lane;

    if (!final_hop) {
        upd_out[idx] = __float22half2_rn(make_float2(gx, gy));
    } else {
        float rsum = rs[r] * inv;
        float s0 = 1.f / (1.f + __expf(-cheb[0]));
        float s1 = 1.f / (1.f + __expf(-cheb[1]));
        float c0 = 1.f - BETA * rsum;
        float c1 = 1.f - BETA * rsum * s0;
        float c2 = 1.f - BETA * rsum * s0 * s1;
        float2 xv = __half22float2(xh[idx]);
        float2 g1 = __half22float2(g1h[idx]);
        float2 g2 = __half22float2(upd_in[idx]);
        float2 o;
        o.x = 0.001f * xv.x + 0.009f * c0 * g1.x + 0.09f * c1 * g2.x + 0.9f * c2 * gx;
        o.y = 0.001f * xv.y + 0.009f * c0 * g1.y + 0.09f * c1 * g2.y + 0.9f * c2 * gy;
        ((float2*)out)[idx] = o;
    }
}

extern "C" void kernel_launch(void* const* d_in, const int* in_sizes, int n_in,
                              void* d_out, int out_size, void* d_ws, size_t ws_size,
                              hipStream_t stream) {
    const float* x    = (const float*)d_in[0];
    const float* a    = (const float*)d_in[2];
    const float* cheb = (const float*)d_in[4];
    const float* adj  = (const float*)d_in[5];
    const int*   erow = (const int*)d_in[6];
    const int*   ecol = (const int*)d_in[7];
    int n = in_sizes[0] / F;
    int e = in_sizes[5];
    float* out = (float*)d_out;
    int nb = (n + RB - 1) >> RSH;

    // workspace layout (4-byte words); only alias: binned -> u2h (dead before hop1 writes u2h)
    float* ws = (float*)d_ws;
    size_t NH = (size_t)n * 64;               // half2 words per feature buffer
    int2*    csr  = (int2*)ws;                // 2E words
    __half2* xh   = (__half2*)(ws + 2 * (size_t)e);
    __half2* u1h  = xh + NH;
    __half2* u2h  = u1h + NH;
    int2*    binned = (int2*)u2h;             // E int2, dead after build_csr
    float* f1     = (float*)(u2h + NH);
    float* f2     = f1 + n;
    float* sden   = f2 + n;
    float* rs     = sden + n;
    int*   rowptr = (int*)(rs + n);           // n+1
    int*   bcnt   = rowptr + n + 1;           // nb (<=512)
    int*   bbase  = bcnt + 512;               // nb+1
    int*   bcur   = bbase + 513;              // nb+1

    int wave_blocks = (n + 3) / 4;

    hipMemsetAsync(bcnt, 0, (size_t)nb * sizeof(int), stream);
    hipLaunchKernelGGL(featconv_hist, dim3(wave_blocks), dim3(256), 0, stream,
                       x, a, f1, f2, xh, n, erow, bcnt, e, nb);
    hipLaunchKernelGGL(bucket_scan, dim3(1), dim3(256), 0, stream, bcnt, bbase, bcur, rowptr + n, nb, e);
    hipLaunchKernelGGL(bin_edges, dim3((e + BT - 1) / BT), dim3(256), 0, stream,
                       erow, ecol, adj, bcur, binned, e);
    hipLaunchKernelGGL(build_csr, dim3(nb), dim3(256), 0, stream,
                       binned, bbase, f1, f2, csr, rowptr, sden, rs, n);

    // hop 0: g1 = norm(U) @ xh              (final_hop = 0)
    hipLaunchKernelGGL(spmm_fuse, dim3(wave_blocks), dim3(256), 0, stream,
                       xh, u1h, (const __half2*)nullptr, (const __half2*)nullptr,
                       (float*)nullptr, csr, rowptr, sden, rs, cheb, n, 0);
    // hop 1: g2 = norm(U) @ g1              (final_hop = 0)
    hipLaunchKernelGGL(spmm_fuse, dim3(wave_blocks), dim3(256), 0, stream,
                       u1h, u2h, (const __half2*)nullptr, (const __half2*)nullptr,
                       (float*)nullptr, csr, rowptr, sden, rs, cheb, n, 0);
    // hop 2: g3 gather + fused final epilogue (final_hop = 1)
    hipLaunchKernelGGL(spmm_fuse, dim3(wave_blocks), dim3(256), 0, stream,
                       u2h, (__half2*)nullptr, xh, u1h,
                       out, csr, rowptr, sden, rs, cheb, n, 1);
}